// Round 3
// baseline (1331.034 us; speedup 1.0000x reference)
//
#include <hip/hip_runtime.h>

// PointNet Set Abstraction (B=16, N=4096, S=1024, K=32, D=64, mlp 67->64->64->128)
// ALL buffers float32 (per the reference file: jnp.float32 in/out). Values are
// bf16-rounded by the dataset, but layout is f32 — rounds 1-2 failed because
// the buffers were misread as u16 bf16 (random mantissa halves -> NaN).
//
// Kernel 1: fps       — 1 block/batch, xyz cached in LDS, exact-order fp32
//                       distances (__f*_rn, numpy op order) + first-index-
//                       tiebreak argmax. Writes new_xyz (exact passthrough).
// Kernel 2: group_mlp — 1 block per (b,s): ballot-based first-K ball query,
//                       gather+concat into LDS, f32 weight staging in a reused
//                       LDS buffer, 3 conv/BN/ReLU layers, max over K.

typedef unsigned int   u32;
typedef unsigned long long u64;

#define NB 16
#define NP 4096
#define NS 1024
#define NK 32

// ---------------------------------------------------------------- FPS
__global__ __launch_bounds__(512) void fps_kernel(
    const float* __restrict__ xyz, float* __restrict__ out0)
{
  __shared__ float lx[NP], ly[NP], lz[NP];
  __shared__ u64 red[8];
  __shared__ int s_idx[NS];
  __shared__ int s_last;
  const int b = blockIdx.x;
  const int t = threadIdx.x;

  const float* bx = xyz + (size_t)b * NP * 3;
  for (int i = t; i < NP; i += 512) {
    lx[i] = bx[i * 3 + 0];
    ly[i] = bx[i * 3 + 1];
    lz[i] = bx[i * 3 + 2];
  }
  if (t == 0) { s_idx[0] = 0; s_last = 0; }
  __syncthreads();

  float px[8], py[8], pz[8], md[8];
#pragma unroll
  for (int p = 0; p < 8; ++p) {
    int i = t * 8 + p;
    px[p] = lx[i]; py[p] = ly[i]; pz[p] = lz[i];
    md[p] = 1e10f;
  }
  const int lane = t & 63, wave = t >> 6;

  for (int it = 1; it < NS; ++it) {
    int last = s_last;
    float cx = lx[last], cy = ly[last], cz = lz[last];
    u64 best = 0;
#pragma unroll
    for (int p = 0; p < 8; ++p) {
      float dx = __fsub_rn(px[p], cx);
      float dy = __fsub_rn(py[p], cy);
      float dz = __fsub_rn(pz[p], cz);
      float d  = __fadd_rn(__fadd_rn(__fmul_rn(dx, dx), __fmul_rn(dy, dy)), __fmul_rn(dz, dz));
      float m2 = fminf(md[p], d);
      md[p] = m2;
      // d >= 0 always -> f32 bits are order-isomorphic; tie -> max ~idx = min idx
      u64 key = (((u64)__float_as_uint(m2)) << 32) | (u32)(~(u32)(t * 8 + p));
      best = best > key ? best : key;
    }
#pragma unroll
    for (int off = 32; off >= 1; off >>= 1) {
      u64 o = __shfl_down(best, off);
      best = best > o ? best : o;
    }
    if (lane == 0) red[wave] = best;
    __syncthreads();
    if (t == 0) {
      u64 bb = red[0];
#pragma unroll
      for (int w = 1; w < 8; ++w) { u64 o = red[w]; bb = bb > o ? bb : o; }
      int idx = (int)(~(u32)bb);
      s_idx[it] = idx;
      s_last = idx;
    }
    __syncthreads();
  }

  for (int e = t; e < NS; e += 512) {
    int id = s_idx[e];
    size_t o = (size_t)(b * NS + e) * 3;
    out0[o + 0] = lx[id];
    out0[o + 1] = ly[id];
    out0[o + 2] = lz[id];   // exact f32 passthrough
  }
}

// ---------------------------------------------------------------- ball query + gather + MLP + max
__global__ __launch_bounds__(256) void group_mlp_kernel(
    const float* __restrict__ xyz, const float* __restrict__ pts,
    const float* __restrict__ nx,                       // = out0 (f32 new_xyz)
    const float* __restrict__ W0, const float* __restrict__ b0, const float* __restrict__ g0,
    const float* __restrict__ be0, const float* __restrict__ m0, const float* __restrict__ v0,
    const float* __restrict__ W1, const float* __restrict__ b1, const float* __restrict__ g1,
    const float* __restrict__ be1, const float* __restrict__ m1, const float* __restrict__ v1,
    const float* __restrict__ W2, const float* __restrict__ b2, const float* __restrict__ g2,
    const float* __restrict__ be2, const float* __restrict__ m2, const float* __restrict__ v2,
    float* __restrict__ out1)
{
  __shared__ __align__(16) float wbuf[4352];   // W0(4288) / W1(4096) / half-W2(4096)
  __shared__ __align__(16) float x0[NK * 67];  // stride 67 (odd -> conflict-free)
  __shared__ __align__(16) float x1[NK * 65];  // stride 65
  __shared__ float sAB[512];                   // A0@0 Bc0@64 A1@128 Bc1@192 A2@256 Bc2@384
  __shared__ u64 masks[64];
  __shared__ int offs[64];
  __shared__ int idx_ls[NK];

  const int bs = blockIdx.x;
  const int b = bs >> 10;
  const int t = threadIdx.x;
  const int lane = t & 63, wave = t >> 6;

  const float cx = nx[(size_t)bs * 3 + 0];
  const float cy = nx[(size_t)bs * 3 + 1];
  const float cz = nx[(size_t)bs * 3 + 2];
  const float R2 = (float)(0.2 * 0.2);   // decision-equivalent to the fp64 compare

  const float* bx = xyz + (size_t)b * NP * 3;

  // --- phase A: hit masks per 64-point chunk
  for (int c = 0; c < 16; ++c) {
    int i = wave * 1024 + c * 64 + lane;
    float dx = __fsub_rn(cx, bx[i * 3 + 0]);
    float dy = __fsub_rn(cy, bx[i * 3 + 1]);
    float dz = __fsub_rn(cz, bx[i * 3 + 2]);
    float d2 = __fadd_rn(__fadd_rn(__fmul_rn(dx, dx), __fmul_rn(dy, dy)), __fmul_rn(dz, dz));
    u64 m = __ballot(d2 < R2);
    if (lane == 0) masks[wave * 16 + c] = m;
  }
  if (t < NK) idx_ls[t] = -1;

  // --- BN fold (A, Bc) for all 3 layers (one channel-slot per thread)
  {
    const float *gp, *bep, *mp, *vp, *bp; int c, base, bcoff;
    if (t < 64)       { c = t;       gp = g0; bep = be0; mp = m0; vp = v0; bp = b0; base = 0;   bcoff = 64;  }
    else if (t < 128) { c = t - 64;  gp = g1; bep = be1; mp = m1; vp = v1; bp = b1; base = 128; bcoff = 64;  }
    else              { c = t - 128; gp = g2; bep = be2; mp = m2; vp = v2; bp = b2; base = 256; bcoff = 128; }
    float a = gp[c] / sqrtf(vp[c] + 1e-5f);
    sAB[base + c] = a;
    sAB[base + bcoff + c] = (bp[c] - mp[c]) * a + bep[c];   // y = relu(dot*A + Bc)
  }
  // --- stage W0 into wbuf (float4 copies; 4288 = 1072 float4)
  {
    const float4* src = (const float4*)W0;
    float4* dst = (float4*)wbuf;
    for (int i = t; i < 1072; i += 256) dst[i] = src[i];
  }
  __syncthreads();

  // exclusive prefix over 64 chunk counts (wave 0)
  if (wave == 0) {
    int cnt = __popcll(masks[lane]);
    int inc = cnt;
#pragma unroll
    for (int off = 1; off < 64; off <<= 1) {
      int n = __shfl_up(inc, off);
      if (lane >= off) inc += n;
    }
    offs[lane] = inc - cnt;
  }
  __syncthreads();

  // first-K slots in global index order
  for (int c = 0; c < 16; ++c) {
    int ch = wave * 16 + c;
    int base = offs[ch];
    if (base >= NK) continue;
    u64 m = masks[ch];
    if ((m >> lane) & 1ull) {
      int slot = base + __popcll(m & ((1ull << lane) - 1ull));
      if (slot < NK) idx_ls[slot] = wave * 1024 + c * 64 + lane;
    }
  }
  __syncthreads();

  // --- phase B: gather concat [xyz_norm(3) | points(64)] into x0
  {
    int kk = t >> 3, cg = t & 7;                 // 32 rows x 8 col-groups
    int id = idx_ls[kk];
    int row = (id < 0) ? (NP - 1) : id;          // torch -1 wrap for points gather
    const float4* p4 = (const float4*)(pts + (((size_t)b * NP + row) * 64 + cg * 8));
    float4 v0 = p4[0], v1 = p4[1];
    float* dst = &x0[kk * 67 + 3 + cg * 8];
    dst[0] = v0.x; dst[1] = v0.y; dst[2] = v0.z; dst[3] = v0.w;
    dst[4] = v1.x; dst[5] = v1.y; dst[6] = v1.z; dst[7] = v1.w;
    if (t < NK) {
      int id2 = idx_ls[t];
      float gx, gy, gz;
      if (id2 >= 0) {
        gx = __fsub_rn(bx[id2 * 3 + 0], cx);
        gy = __fsub_rn(bx[id2 * 3 + 1], cy);
        gz = __fsub_rn(bx[id2 * 3 + 2], cz);
      } else {                                    // padded: grouped_xyz=0 -> 0 - new_xyz
        gx = 0.0f - cx; gy = 0.0f - cy; gz = 0.0f - cz;
      }
      x0[t * 67 + 0] = gx; x0[t * 67 + 1] = gy; x0[t * 67 + 2] = gz;
    }
  }
  __syncthreads();

  const int k  = t & 31;      // row (neighbor slot)
  const int jg = t >> 5;      // column group 0..7

  // --- layer 1: 67 -> 64 (wbuf = W0), out x1
  {
    int j0 = jg * 8;
    float acc[8] = {0, 0, 0, 0, 0, 0, 0, 0};
    const float* xr = &x0[k * 67];
    for (int c = 0; c < 67; ++c) {
      float xv = xr[c];
      const float4* wp = (const float4*)(wbuf + c * 64 + j0);
      float4 w0 = wp[0], w1 = wp[1];
      acc[0] = fmaf(xv, w0.x, acc[0]); acc[1] = fmaf(xv, w0.y, acc[1]);
      acc[2] = fmaf(xv, w0.z, acc[2]); acc[3] = fmaf(xv, w0.w, acc[3]);
      acc[4] = fmaf(xv, w1.x, acc[4]); acc[5] = fmaf(xv, w1.y, acc[5]);
      acc[6] = fmaf(xv, w1.z, acc[6]); acc[7] = fmaf(xv, w1.w, acc[7]);
    }
#pragma unroll
    for (int u = 0; u < 8; ++u) {
      float y = fmaf(acc[u], sAB[0 + j0 + u], sAB[64 + j0 + u]);
      x1[k * 65 + j0 + u] = fmaxf(y, 0.0f);
    }
  }
  __syncthreads();

  // --- stage W1 (4096 floats = 1024 float4)
  {
    const float4* src = (const float4*)W1;
    float4* dst = (float4*)wbuf;
    for (int i = t; i < 1024; i += 256) dst[i] = src[i];
  }
  __syncthreads();

  // --- layer 2: 64 -> 64 (wbuf = W1), out reuses x0 (stride 65)
  {
    int j0 = jg * 8;
    float acc[8] = {0, 0, 0, 0, 0, 0, 0, 0};
    const float* xr = &x1[k * 65];
    for (int c = 0; c < 64; ++c) {
      float xv = xr[c];
      const float4* wp = (const float4*)(wbuf + c * 64 + j0);
      float4 w0 = wp[0], w1 = wp[1];
      acc[0] = fmaf(xv, w0.x, acc[0]); acc[1] = fmaf(xv, w0.y, acc[1]);
      acc[2] = fmaf(xv, w0.z, acc[2]); acc[3] = fmaf(xv, w0.w, acc[3]);
      acc[4] = fmaf(xv, w1.x, acc[4]); acc[5] = fmaf(xv, w1.y, acc[5]);
      acc[6] = fmaf(xv, w1.z, acc[6]); acc[7] = fmaf(xv, w1.w, acc[7]);
    }
#pragma unroll
    for (int u = 0; u < 8; ++u) {
      float y = fmaf(acc[u], sAB[128 + j0 + u], sAB[192 + j0 + u]);
      x0[k * 65 + j0 + u] = fmaxf(y, 0.0f);
    }
  }
  __syncthreads();

  // --- layer 3: 64 -> 128 (W2 staged in two 32-row halves) + max over k
  {
    int j0 = jg * 16;
    float acc[16];
#pragma unroll
    for (int u = 0; u < 16; ++u) acc[u] = 0.0f;
    for (int h = 0; h < 2; ++h) {
      const float4* src = (const float4*)(W2 + h * 4096);
      float4* dst = (float4*)wbuf;
      for (int i = t; i < 1024; i += 256) dst[i] = src[i];
      __syncthreads();
      const float* xr = &x0[k * 65 + h * 32];
      for (int c = 0; c < 32; ++c) {
        float xv = xr[c];
        const float4* wp = (const float4*)(wbuf + c * 128 + j0);
        float4 w0 = wp[0], w1 = wp[1], w2 = wp[2], w3 = wp[3];
        acc[0]  = fmaf(xv, w0.x, acc[0]);  acc[1]  = fmaf(xv, w0.y, acc[1]);
        acc[2]  = fmaf(xv, w0.z, acc[2]);  acc[3]  = fmaf(xv, w0.w, acc[3]);
        acc[4]  = fmaf(xv, w1.x, acc[4]);  acc[5]  = fmaf(xv, w1.y, acc[5]);
        acc[6]  = fmaf(xv, w1.z, acc[6]);  acc[7]  = fmaf(xv, w1.w, acc[7]);
        acc[8]  = fmaf(xv, w2.x, acc[8]);  acc[9]  = fmaf(xv, w2.y, acc[9]);
        acc[10] = fmaf(xv, w2.z, acc[10]); acc[11] = fmaf(xv, w2.w, acc[11]);
        acc[12] = fmaf(xv, w3.x, acc[12]); acc[13] = fmaf(xv, w3.y, acc[13]);
        acc[14] = fmaf(xv, w3.z, acc[14]); acc[15] = fmaf(xv, w3.w, acc[15]);
      }
      __syncthreads();
    }
    float mx[16];
#pragma unroll
    for (int u = 0; u < 16; ++u) {
      float y = fmaf(acc[u], sAB[256 + j0 + u], sAB[384 + j0 + u]);
      mx[u] = fmaxf(y, 0.0f);
    }
#pragma unroll
    for (int off = 16; off >= 1; off >>= 1) {
#pragma unroll
      for (int u = 0; u < 16; ++u)
        mx[u] = fmaxf(mx[u], __shfl_down(mx[u], off, 32));
    }
    if ((t & 31) == 0) {
      float* op = out1 + (size_t)bs * 128 + j0;
#pragma unroll
      for (int u = 0; u < 16; ++u) op[u] = mx[u];
    }
  }
}

// ---------------------------------------------------------------- launcher
extern "C" void kernel_launch(void* const* d_in, const int* in_sizes, int n_in,
                              void* d_out, int out_size, void* d_ws, size_t ws_size,
                              hipStream_t stream) {
  const float* xyz = (const float*)d_in[0];
  const float* pts = (const float*)d_in[1];
  const float* W0 = (const float*)d_in[2];  const float* b0 = (const float*)d_in[3];
  const float* g0 = (const float*)d_in[4];  const float* be0 = (const float*)d_in[5];
  const float* m0 = (const float*)d_in[6];  const float* v0 = (const float*)d_in[7];
  const float* W1 = (const float*)d_in[8];  const float* b1 = (const float*)d_in[9];
  const float* g1 = (const float*)d_in[10]; const float* be1 = (const float*)d_in[11];
  const float* m1 = (const float*)d_in[12]; const float* v1 = (const float*)d_in[13];
  const float* W2 = (const float*)d_in[14]; const float* b2 = (const float*)d_in[15];
  const float* g2 = (const float*)d_in[16]; const float* be2 = (const float*)d_in[17];
  const float* m2 = (const float*)d_in[18]; const float* v2 = (const float*)d_in[19];

  float* out0 = (float*)d_out;           // new_xyz    (B,S,3)
  float* out1 = out0 + NB * NS * 3;      // new_points (B,S,128)

  fps_kernel<<<NB, 512, 0, stream>>>(xyz, out0);

  group_mlp_kernel<<<NB * NS, 256, 0, stream>>>(
      xyz, pts, out0,
      W0, b0, g0, be0, m0, v0,
      W1, b1, g1, be1, m1, v1,
      W2, b2, g2, be2, m2, v2,
      out1);
}

// Round 4
// 1060.723 us; speedup vs baseline: 1.2548x; 1.2548x over previous
//
#include <hip/hip_runtime.h>

// PointNet Set Abstraction (B=16, N=4096, S=1024, K=32, D=64, mlp 67->64->64->128)
// All buffers float32. Exact-semantics fp32 (__f*_rn, numpy op order) for all
// DECISIONS (FPS argmax w/ first-index tiebreak, ball-query first-K).
//
// R4: fps — DPP wave reductions + single barrier/iter (double-buffered keys),
//           packed float4 coord LDS, per-iter out0 store.
//     group_mlp — 2 centroids/block, 64 rows = 64 lanes, wave-uniform weight
//           addresses (scalar loads, no weight LDS), DPP max-pool.

typedef unsigned int   u32;
typedef unsigned long long u64;

#define NB 16
#define NP 4096
#define NS 1024
#define NK 32

// DPP helpers. update_dpp(old=v, src=v, ctrl, 0xf, 0xf, false): invalid-source
// lanes yield v (or 0 under the other bound_ctrl reading) — both reductions
// below use identity 0, so either semantic is correct.
#define DPP_UPD(v, ctrl) ((u32)__builtin_amdgcn_update_dpp((int)(v), (int)(v), (ctrl), 0xf, 0xf, false))
#define RED_STEP_MAX(v, ctrl) { u32 _o = DPP_UPD(v, ctrl); v = (v > _o) ? v : _o; }
// full-wave (64 lane) max -> lane 63
#define WAVE_RED_UMAX64(v) do { \
  RED_STEP_MAX(v, 0x111); RED_STEP_MAX(v, 0x112); RED_STEP_MAX(v, 0x114); \
  RED_STEP_MAX(v, 0x118); RED_STEP_MAX(v, 0x142); RED_STEP_MAX(v, 0x143); } while (0)
// 32-lane-half max -> lane 31 (rows 0-31) and lane 63 (rows 32-63)
#define HALF_RED_UMAX32(v) do { \
  RED_STEP_MAX(v, 0x111); RED_STEP_MAX(v, 0x112); RED_STEP_MAX(v, 0x114); \
  RED_STEP_MAX(v, 0x118); RED_STEP_MAX(v, 0x142); } while (0)

// ---------------------------------------------------------------- FPS
__global__ __launch_bounds__(256) void fps_kernel(
    const float* __restrict__ xyz, float* __restrict__ out0)
{
  __shared__ __align__(16) float4 pxyz[NP];   // 64 KB
  __shared__ u64 red[2][4];                   // double-buffered per-wave keys
  const int b = blockIdx.x;
  const int t = threadIdx.x;
  const int lane = t & 63, wv = t >> 6;

  const float* bx = xyz + (size_t)b * NP * 3;
  for (int i = t; i < NP; i += 256)
    pxyz[i] = make_float4(bx[i * 3 + 0], bx[i * 3 + 1], bx[i * 3 + 2], 0.0f);
  __syncthreads();

  float px[16], py[16], pz[16], md[16];
#pragma unroll
  for (int p = 0; p < 16; ++p) {
    float4 v = pxyz[t * 16 + p];
    px[p] = v.x; py[p] = v.y; pz[p] = v.z;
    md[p] = 1e10f;
  }
  float4 cc = pxyz[0];
  if (t == 0) {
    size_t o = (size_t)b * NS * 3;
    out0[o + 0] = cc.x; out0[o + 1] = cc.y; out0[o + 2] = cc.z;
  }

  for (int it = 1; it < NS; ++it) {
    const float cx = cc.x, cy = cc.y, cz = cc.z;
    u32 vb = 0;   // max of float bits (dists >= 0 -> order-isomorphic)
#pragma unroll
    for (int p = 0; p < 16; ++p) {
      float dx = __fsub_rn(px[p], cx);
      float dy = __fsub_rn(py[p], cy);
      float dz = __fsub_rn(pz[p], cz);
      float d  = __fadd_rn(__fadd_rn(__fmul_rn(dx, dx), __fmul_rn(dy, dy)), __fmul_rn(dz, dz));
      float m2 = fminf(md[p], d);
      md[p] = m2;
      u32 mb = __float_as_uint(m2);
      vb = (vb > mb) ? vb : mb;
    }
    WAVE_RED_UMAX64(vb);
    const u32 wmax = (u32)__builtin_amdgcn_readlane((int)vb, 63);
    // candidate = max of ~idx among md[p]==wmax (identity 0); max ~idx = min idx
    u32 ca = 0;
#pragma unroll
    for (int p = 0; p < 16; ++p) {
      u32 c = (__float_as_uint(md[p]) == wmax) ? ~(u32)(t * 16 + p) : 0u;
      ca = (ca > c) ? ca : c;
    }
    WAVE_RED_UMAX64(ca);
    const u32 wca = (u32)__builtin_amdgcn_readlane((int)ca, 63);
    const int par = it & 1;
    if (lane == 0) red[par][wv] = (((u64)wmax) << 32) | wca;
    __syncthreads();
    u64 k0 = red[par][0], k1 = red[par][1], k2 = red[par][2], k3 = red[par][3];
    u64 ba = (k0 > k1) ? k0 : k1;
    u64 bb = (k2 > k3) ? k2 : k3;
    u64 bk = (ba > bb) ? ba : bb;
    const int idx = (int)(~(u32)bk);
    cc = pxyz[idx];
    if (t == 0) {
      size_t o = ((size_t)b * NS + it) * 3;
      out0[o + 0] = cc.x; out0[o + 1] = cc.y; out0[o + 2] = cc.z;
    }
    // no second barrier: red[par] next written at it+2, after barrier at it+1
  }
}

// ---------------------------------------------------------------- ball query + gather + MLP + max
// One block per 2 centroids. Rows: lane 0-31 = cent0, 32-63 = cent1.
// Wave w covers cols [w*16, w*16+16) (layers 1-2) / [w*32, w*32+32) (layer 3).
__global__ __launch_bounds__(256, 4) void group_mlp_kernel(
    const float* __restrict__ xyz, const float* __restrict__ pts,
    const float* __restrict__ nx,
    const float* __restrict__ W0, const float* __restrict__ b0, const float* __restrict__ g0,
    const float* __restrict__ be0, const float* __restrict__ m0, const float* __restrict__ v0,
    const float* __restrict__ W1, const float* __restrict__ b1, const float* __restrict__ g1,
    const float* __restrict__ be1, const float* __restrict__ m1, const float* __restrict__ v1,
    const float* __restrict__ W2, const float* __restrict__ b2, const float* __restrict__ g2,
    const float* __restrict__ be2, const float* __restrict__ m2, const float* __restrict__ v2,
    float* __restrict__ out1)
{
  __shared__ __align__(16) float x0[64 * 67];  // stride 67
  __shared__ __align__(16) float x1[64 * 65];  // stride 65 (layer2 out reuses x0 @65)
  __shared__ float sAB[512];   // A0@0 B0@64 A1@128 B1@192 A2@256 B2@384
  __shared__ u64 masks[2][64];
  __shared__ int offs[2][64];
  __shared__ int idx_ls[2][NK];

  const int bp = blockIdx.x;            // 0..8191
  const int b  = bp >> 9;
  const int s0 = (bp & 511) * 2;
  const int t = threadIdx.x;
  const int lane = t & 63, w = t >> 6;
  const int centw = w >> 1, wsub = w & 1;

  const float* cp = nx + ((size_t)b * NS + s0) * 3;
  const float c0x = cp[0], c0y = cp[1], c0z = cp[2];
  const float c1x = cp[3], c1y = cp[4], c1z = cp[5];
  const float R2 = (float)(0.2 * 0.2);
  const float* bx = xyz + (size_t)b * NP * 3;

  // --- phase A: per-chunk hit masks (waves 0,1 -> cent0; 2,3 -> cent1)
  {
    const float ax = centw ? c1x : c0x;
    const float ay = centw ? c1y : c0y;
    const float az = centw ? c1z : c0z;
    for (int c = 0; c < 32; ++c) {
      int ch = wsub * 32 + c;
      int i = ch * 64 + lane;
      float dx = __fsub_rn(ax, bx[i * 3 + 0]);
      float dy = __fsub_rn(ay, bx[i * 3 + 1]);
      float dz = __fsub_rn(az, bx[i * 3 + 2]);
      float d2 = __fadd_rn(__fadd_rn(__fmul_rn(dx, dx), __fmul_rn(dy, dy)), __fmul_rn(dz, dz));
      u64 m = __ballot(d2 < R2);
      if (lane == 0) masks[centw][ch] = m;
    }
  }
  if (t < 64) idx_ls[t >> 5][t & 31] = -1;

  // --- BN fold (one channel-slot per thread)
  {
    const float *gp, *bep, *mp, *vp, *bpp; int c, base, bcoff;
    if (t < 64)       { c = t;       gp = g0; bep = be0; mp = m0; vp = v0; bpp = b0; base = 0;   bcoff = 64;  }
    else if (t < 128) { c = t - 64;  gp = g1; bep = be1; mp = m1; vp = v1; bpp = b1; base = 128; bcoff = 64;  }
    else              { c = t - 128; gp = g2; bep = be2; mp = m2; vp = v2; bpp = b2; base = 256; bcoff = 128; }
    float a = gp[c] / sqrtf(vp[c] + 1e-5f);
    sAB[base + c] = a;
    sAB[base + bcoff + c] = (bpp[c] - mp[c]) * a + bep[c];
  }
  __syncthreads();

  // --- prefix over 64 chunk counts (wave 0 -> cent0, wave 2 -> cent1)
  if ((w & 1) == 0) {
    int cent = centw;
    int cnt = __popcll(masks[cent][lane]);
    int inc = cnt;
#pragma unroll
    for (int off = 1; off < 64; off <<= 1) {
      int n = __shfl_up(inc, off);
      if (lane >= off) inc += n;
    }
    offs[cent][lane] = inc - cnt;
  }
  __syncthreads();

  // --- first-K slots in global index order
  for (int c = 0; c < 32; ++c) {
    int ch = wsub * 32 + c;
    int base = offs[centw][ch];
    if (base >= NK) continue;
    u64 m = masks[centw][ch];
    if ((m >> lane) & 1ull) {
      int slot = base + __popcll(m & ((1ull << lane) - 1ull));
      if (slot < NK) idx_ls[centw][slot] = ch * 64 + lane;
    }
  }
  __syncthreads();

  // --- gather concat [xyz_norm(3) | points(64)] into x0 (64 rows x 67)
  {
    int cent = t >> 7, tt = t & 127;
    int row = tt >> 2, q = tt & 3;               // 32 rows x 4 col-quarters
    int id = idx_ls[cent][row];
    int prow = (id < 0) ? (NP - 1) : id;         // torch -1 wrap
    const float4* p4 = (const float4*)(pts + ((size_t)b * NP + prow) * 64 + q * 16);
    float4 va = p4[0], vb = p4[1], vc = p4[2], vd = p4[3];
    float* dst = &x0[(cent * 32 + row) * 67 + 3 + q * 16];
    dst[0]  = va.x; dst[1]  = va.y; dst[2]  = va.z; dst[3]  = va.w;
    dst[4]  = vb.x; dst[5]  = vb.y; dst[6]  = vb.z; dst[7]  = vb.w;
    dst[8]  = vc.x; dst[9]  = vc.y; dst[10] = vc.z; dst[11] = vc.w;
    dst[12] = vd.x; dst[13] = vd.y; dst[14] = vd.z; dst[15] = vd.w;
    if (t < 64) {
      int c2 = t >> 5, slot = t & 31;
      int id2 = idx_ls[c2][slot];
      float ax = c2 ? c1x : c0x, ay = c2 ? c1y : c0y, az = c2 ? c1z : c0z;
      float gx, gy, gz;
      if (id2 >= 0) {
        gx = __fsub_rn(bx[id2 * 3 + 0], ax);
        gy = __fsub_rn(bx[id2 * 3 + 1], ay);
        gz = __fsub_rn(bx[id2 * 3 + 2], az);
      } else {
        gx = 0.0f - ax; gy = 0.0f - ay; gz = 0.0f - az;
      }
      float* d2p = &x0[(c2 * 32 + slot) * 67];
      d2p[0] = gx; d2p[1] = gy; d2p[2] = gz;
    }
  }
  __syncthreads();

  const int j0 = __builtin_amdgcn_readfirstlane(w * 16);   // wave-uniform col base
  const int R = lane;                                       // row 0..63

  // --- layer 1: 67 -> 64 (weights direct from global, uniform address)
  {
    float acc[16];
#pragma unroll
    for (int i = 0; i < 16; ++i) acc[i] = 0.0f;
    const float* xr = &x0[R * 67];
    for (int c = 0; c < 67; ++c) {
      float xv = xr[c];
      const float4* wr = (const float4*)(W0 + c * 64 + j0);
      float4 wa = wr[0], wb = wr[1], wc = wr[2], wd = wr[3];
      acc[0]  = fmaf(xv, wa.x, acc[0]);  acc[1]  = fmaf(xv, wa.y, acc[1]);
      acc[2]  = fmaf(xv, wa.z, acc[2]);  acc[3]  = fmaf(xv, wa.w, acc[3]);
      acc[4]  = fmaf(xv, wb.x, acc[4]);  acc[5]  = fmaf(xv, wb.y, acc[5]);
      acc[6]  = fmaf(xv, wb.z, acc[6]);  acc[7]  = fmaf(xv, wb.w, acc[7]);
      acc[8]  = fmaf(xv, wc.x, acc[8]);  acc[9]  = fmaf(xv, wc.y, acc[9]);
      acc[10] = fmaf(xv, wc.z, acc[10]); acc[11] = fmaf(xv, wc.w, acc[11]);
      acc[12] = fmaf(xv, wd.x, acc[12]); acc[13] = fmaf(xv, wd.y, acc[13]);
      acc[14] = fmaf(xv, wd.z, acc[14]); acc[15] = fmaf(xv, wd.w, acc[15]);
    }
#pragma unroll
    for (int i = 0; i < 16; ++i) {
      float y = fmaf(acc[i], sAB[j0 + i], sAB[64 + j0 + i]);
      x1[R * 65 + j0 + i] = fmaxf(y, 0.0f);
    }
  }
  __syncthreads();

  // --- layer 2: 64 -> 64, out into x0 region (stride 65)
  {
    float acc[16];
#pragma unroll
    for (int i = 0; i < 16; ++i) acc[i] = 0.0f;
    const float* xr = &x1[R * 65];
    for (int c = 0; c < 64; ++c) {
      float xv = xr[c];
      const float4* wr = (const float4*)(W1 + c * 64 + j0);
      float4 wa = wr[0], wb = wr[1], wc = wr[2], wd = wr[3];
      acc[0]  = fmaf(xv, wa.x, acc[0]);  acc[1]  = fmaf(xv, wa.y, acc[1]);
      acc[2]  = fmaf(xv, wa.z, acc[2]);  acc[3]  = fmaf(xv, wa.w, acc[3]);
      acc[4]  = fmaf(xv, wb.x, acc[4]);  acc[5]  = fmaf(xv, wb.y, acc[5]);
      acc[6]  = fmaf(xv, wb.z, acc[6]);  acc[7]  = fmaf(xv, wb.w, acc[7]);
      acc[8]  = fmaf(xv, wc.x, acc[8]);  acc[9]  = fmaf(xv, wc.y, acc[9]);
      acc[10] = fmaf(xv, wc.z, acc[10]); acc[11] = fmaf(xv, wc.w, acc[11]);
      acc[12] = fmaf(xv, wd.x, acc[12]); acc[13] = fmaf(xv, wd.y, acc[13]);
      acc[14] = fmaf(xv, wd.z, acc[14]); acc[15] = fmaf(xv, wd.w, acc[15]);
    }
#pragma unroll
    for (int i = 0; i < 16; ++i) {
      float y = fmaf(acc[i], sAB[128 + j0 + i], sAB[192 + j0 + i]);
      x0[R * 65 + j0 + i] = fmaxf(y, 0.0f);
    }
  }
  __syncthreads();

  // --- layer 3: 64 -> 128 + max over 32 rows per centroid (DPP halves)
  {
    const int j3 = __builtin_amdgcn_readfirstlane(w * 32);
    float acc[32];
#pragma unroll
    for (int i = 0; i < 32; ++i) acc[i] = 0.0f;
    const float* xr = &x0[R * 65];
    for (int c = 0; c < 64; ++c) {
      float xv = xr[c];
      const float4* wr = (const float4*)(W2 + c * 128 + j3);
#pragma unroll
      for (int q = 0; q < 8; ++q) {
        float4 wq = wr[q];
        acc[q * 4 + 0] = fmaf(xv, wq.x, acc[q * 4 + 0]);
        acc[q * 4 + 1] = fmaf(xv, wq.y, acc[q * 4 + 1]);
        acc[q * 4 + 2] = fmaf(xv, wq.z, acc[q * 4 + 2]);
        acc[q * 4 + 3] = fmaf(xv, wq.w, acc[q * 4 + 3]);
      }
    }
#pragma unroll
    for (int i = 0; i < 32; ++i) {
      float y = fmaf(acc[i], sAB[256 + j3 + i], sAB[384 + j3 + i]);
      u32 mb = __float_as_uint(fmaxf(y, 0.0f));   // >=0 -> bits order-isomorphic; identity 0 safe
      HALF_RED_UMAX32(mb);
      acc[i] = __uint_as_float(mb);
    }
    if (lane == 31 || lane == 63) {
      int cent = lane >> 5;
      float4* op = (float4*)(out1 + ((size_t)b * NS + s0 + cent) * 128 + j3);
#pragma unroll
      for (int q = 0; q < 8; ++q)
        op[q] = make_float4(acc[q * 4 + 0], acc[q * 4 + 1], acc[q * 4 + 2], acc[q * 4 + 3]);
    }
  }
}

// ---------------------------------------------------------------- launcher
extern "C" void kernel_launch(void* const* d_in, const int* in_sizes, int n_in,
                              void* d_out, int out_size, void* d_ws, size_t ws_size,
                              hipStream_t stream) {
  const float* xyz = (const float*)d_in[0];
  const float* pts = (const float*)d_in[1];
  const float* W0 = (const float*)d_in[2];  const float* b0 = (const float*)d_in[3];
  const float* g0 = (const float*)d_in[4];  const float* be0 = (const float*)d_in[5];
  const float* m0 = (const float*)d_in[6];  const float* v0 = (const float*)d_in[7];
  const float* W1 = (const float*)d_in[8];  const float* b1 = (const float*)d_in[9];
  const float* g1 = (const float*)d_in[10]; const float* be1 = (const float*)d_in[11];
  const float* m1 = (const float*)d_in[12]; const float* v1 = (const float*)d_in[13];
  const float* W2 = (const float*)d_in[14]; const float* b2 = (const float*)d_in[15];
  const float* g2 = (const float*)d_in[16]; const float* be2 = (const float*)d_in[17];
  const float* m2 = (const float*)d_in[18]; const float* v2 = (const float*)d_in[19];

  float* out0 = (float*)d_out;           // new_xyz    (B,S,3)
  float* out1 = out0 + NB * NS * 3;      // new_points (B,S,128)

  fps_kernel<<<NB, 256, 0, stream>>>(xyz, out0);

  group_mlp_kernel<<<NB * NS / 2, 256, 0, stream>>>(
      xyz, pts, out0,
      W0, b0, g0, be0, m0, v0,
      W1, b1, g1, be1, m1, v1,
      W2, b2, g2, be2, m2, v2,
      out1);
}

// Round 5
// 1045.474 us; speedup vs baseline: 1.2731x; 1.0146x over previous
//
#include <hip/hip_runtime.h>

// PointNet Set Abstraction (B=16, N=4096, S=1024, K=32, D=64, mlp 67->64->64->128)
// All buffers float32. Exact-semantics fp32 (__f*_rn, numpy op order) for all
// DECISIONS (FPS argmax w/ first-index tiebreak, ball-query first-K).
//
// R5: fps — 512 thr (2 waves/SIMD hides DPP latency), SoA LDS w/ interleaved
//           ownership (conflict-free), fused u64 (dist|~idx) DPP reduction,
//           lane-63 key write, single barrier/iter (double-buffered keys).
//     group_mlp — phase A computes both centroids per point load; unroll-2 on
//           layer c-loops to pipeline scalar weight loads.

typedef unsigned int   u32;
typedef unsigned long long u64;

#define NB 16
#define NP 4096
#define NS 1024
#define NK 32

#define DPP_UPD(v, ctrl) ((u32)__builtin_amdgcn_update_dpp((int)(v), (int)(v), (ctrl), 0xf, 0xf, false))
// one u64-max step: shuffle both halves with same ctrl (coherent pair), 64-bit max
#define U64_STEP(v, ctrl) { \
  u32 _lo = DPP_UPD((u32)(v), ctrl); \
  u32 _hi = DPP_UPD((u32)((v) >> 32), ctrl); \
  u64 _o = (((u64)_hi) << 32) | _lo; \
  v = (v > _o) ? v : _o; }
// full-wave u64 max -> lane 63 (identity 0 under either bound_ctrl semantic)
#define WAVE_RED_U64MAX(v) do { \
  U64_STEP(v, 0x111); U64_STEP(v, 0x112); U64_STEP(v, 0x114); \
  U64_STEP(v, 0x118); U64_STEP(v, 0x142); U64_STEP(v, 0x143); } while (0)

#define RED_STEP_MAX(v, ctrl) { u32 _o = DPP_UPD(v, ctrl); v = (v > _o) ? v : _o; }
// 32-lane-half max -> lane 31 (rows 0-31) and lane 63 (rows 32-63)
#define HALF_RED_UMAX32(v) do { \
  RED_STEP_MAX(v, 0x111); RED_STEP_MAX(v, 0x112); RED_STEP_MAX(v, 0x114); \
  RED_STEP_MAX(v, 0x118); RED_STEP_MAX(v, 0x142); } while (0)

// ---------------------------------------------------------------- FPS
__global__ __launch_bounds__(512) void fps_kernel(
    const float* __restrict__ xyz, float* __restrict__ out0)
{
  __shared__ float lx[NP], ly[NP], lz[NP];   // 48 KB, SoA
  __shared__ u64 red[2][8];                  // double-buffered per-wave keys
  const int b = blockIdx.x;
  const int t = threadIdx.x;
  const int lane = t & 63, wv = t >> 6;

  const float* bx = xyz + (size_t)b * NP * 3;
  for (int i = t; i < NP; i += 512) {
    lx[i] = bx[i * 3 + 0];
    ly[i] = bx[i * 3 + 1];
    lz[i] = bx[i * 3 + 2];
  }
  __syncthreads();

  // interleaved ownership: point p*512+t -> conflict-free LDS access
  float px[8], py[8], pz[8], md[8];
#pragma unroll
  for (int p = 0; p < 8; ++p) {
    int i = p * 512 + t;
    px[p] = lx[i]; py[p] = ly[i]; pz[p] = lz[i];
    md[p] = 1e10f;
  }
  const u32 nt = ~(u32)t;

  float cx = lx[0], cy = ly[0], cz = lz[0];
  if (t == 0) {
    size_t o = (size_t)b * NS * 3;
    out0[o + 0] = cx; out0[o + 1] = cy; out0[o + 2] = cz;
  }

  for (int it = 1; it < NS; ++it) {
    u32 vb, ca;
    {   // p = 0 seeds (all-ties edge -> idx t, global min idx 0, matches numpy)
      float dx = __fsub_rn(px[0], cx);
      float dy = __fsub_rn(py[0], cy);
      float dz = __fsub_rn(pz[0], cz);
      float d  = __fadd_rn(__fadd_rn(__fmul_rn(dx, dx), __fmul_rn(dy, dy)), __fmul_rn(dz, dz));
      float m2 = fminf(md[0], d);
      md[0] = m2;
      vb = __float_as_uint(m2);
      ca = nt;
    }
#pragma unroll
    for (int p = 1; p < 8; ++p) {
      float dx = __fsub_rn(px[p], cx);
      float dy = __fsub_rn(py[p], cy);
      float dz = __fsub_rn(pz[p], cz);
      float d  = __fadd_rn(__fadd_rn(__fmul_rn(dx, dx), __fmul_rn(dy, dy)), __fmul_rn(dz, dz));
      float m2 = fminf(md[p], d);
      md[p] = m2;
      u32 mb = __float_as_uint(m2);
      bool gt = mb > vb;                 // strict > keeps first (smallest) idx on ties
      vb = gt ? mb : vb;
      ca = gt ? (nt - (u32)(p * 512)) : ca;   // ~(p*512+t) = ~t - p*512
    }
    u64 key = (((u64)vb) << 32) | ca;
    WAVE_RED_U64MAX(key);
    const int par = it & 1;
    if (lane == 63) red[par][wv] = key;
    __syncthreads();
    u64 b0 = red[par][0], b1 = red[par][1], b2 = red[par][2], b3 = red[par][3];
    u64 b4 = red[par][4], b5 = red[par][5], b6 = red[par][6], b7 = red[par][7];
    u64 m01 = (b0 > b1) ? b0 : b1;
    u64 m23 = (b2 > b3) ? b2 : b3;
    u64 m45 = (b4 > b5) ? b4 : b5;
    u64 m67 = (b6 > b7) ? b6 : b7;
    u64 ma = (m01 > m23) ? m01 : m23;
    u64 mb2 = (m45 > m67) ? m45 : m67;
    u64 bk = (ma > mb2) ? ma : mb2;
    const int idx = (int)(~(u32)bk);
    cx = lx[idx]; cy = ly[idx]; cz = lz[idx];   // uniform broadcasts
    if (t == 0) {
      size_t o = ((size_t)b * NS + it) * 3;
      out0[o + 0] = cx; out0[o + 1] = cy; out0[o + 2] = cz;
    }
    // no second barrier: red[par] rewritten at it+2, after barrier at it+1
  }
}

// ---------------------------------------------------------------- ball query + gather + MLP + max
// One block per 2 centroids. Rows: lane 0-31 = cent0, 32-63 = cent1.
__global__ __launch_bounds__(256, 4) void group_mlp_kernel(
    const float* __restrict__ xyz, const float* __restrict__ pts,
    const float* __restrict__ nx,
    const float* __restrict__ W0, const float* __restrict__ b0, const float* __restrict__ g0,
    const float* __restrict__ be0, const float* __restrict__ m0, const float* __restrict__ v0,
    const float* __restrict__ W1, const float* __restrict__ b1, const float* __restrict__ g1,
    const float* __restrict__ be1, const float* __restrict__ m1, const float* __restrict__ v1,
    const float* __restrict__ W2, const float* __restrict__ b2, const float* __restrict__ g2,
    const float* __restrict__ be2, const float* __restrict__ m2, const float* __restrict__ v2,
    float* __restrict__ out1)
{
  __shared__ __align__(16) float x0[64 * 67];  // stride 67
  __shared__ __align__(16) float x1[64 * 65];  // stride 65 (layer2 out reuses x0 @65)
  __shared__ float sAB[512];   // A0@0 B0@64 A1@128 B1@192 A2@256 B2@384
  __shared__ u64 masks[2][64];
  __shared__ int offs[2][64];
  __shared__ int idx_ls[2][NK];

  const int bp = blockIdx.x;            // 0..8191
  const int b  = bp >> 9;
  const int s0 = (bp & 511) * 2;
  const int t = threadIdx.x;
  const int lane = t & 63, w = t >> 6;
  const int centw = w >> 1;

  const float* cp = nx + ((size_t)b * NS + s0) * 3;
  const float c0x = cp[0], c0y = cp[1], c0z = cp[2];
  const float c1x = cp[3], c1y = cp[4], c1z = cp[5];
  const float R2 = (float)(0.2 * 0.2);
  const float* bx = xyz + (size_t)b * NP * 3;

  // --- phase A: per-chunk hit masks for BOTH centroids from one point load
  for (int c = 0; c < 16; ++c) {
    int ch = w * 16 + c;
    int i = ch * 64 + lane;
    float X = bx[i * 3 + 0], Y = bx[i * 3 + 1], Z = bx[i * 3 + 2];
    float dx0 = __fsub_rn(c0x, X), dy0 = __fsub_rn(c0y, Y), dz0 = __fsub_rn(c0z, Z);
    float d20 = __fadd_rn(__fadd_rn(__fmul_rn(dx0, dx0), __fmul_rn(dy0, dy0)), __fmul_rn(dz0, dz0));
    u64 mA = __ballot(d20 < R2);
    float dx1 = __fsub_rn(c1x, X), dy1 = __fsub_rn(c1y, Y), dz1 = __fsub_rn(c1z, Z);
    float d21 = __fadd_rn(__fadd_rn(__fmul_rn(dx1, dx1), __fmul_rn(dy1, dy1)), __fmul_rn(dz1, dz1));
    u64 mB = __ballot(d21 < R2);
    if (lane == 0) { masks[0][ch] = mA; masks[1][ch] = mB; }
  }
  if (t < 64) idx_ls[t >> 5][t & 31] = -1;

  // --- BN fold (one channel-slot per thread)
  {
    const float *gp, *bep, *mp, *vp, *bpp; int c, base, bcoff;
    if (t < 64)       { c = t;       gp = g0; bep = be0; mp = m0; vp = v0; bpp = b0; base = 0;   bcoff = 64;  }
    else if (t < 128) { c = t - 64;  gp = g1; bep = be1; mp = m1; vp = v1; bpp = b1; base = 128; bcoff = 64;  }
    else              { c = t - 128; gp = g2; bep = be2; mp = m2; vp = v2; bpp = b2; base = 256; bcoff = 128; }
    float a = gp[c] / sqrtf(vp[c] + 1e-5f);
    sAB[base + c] = a;
    sAB[base + bcoff + c] = (bpp[c] - mp[c]) * a + bep[c];
  }
  __syncthreads();

  // --- prefix over 64 chunk counts (wave 0 -> cent0, wave 2 -> cent1)
  if ((w & 1) == 0) {
    int cent = centw;
    int cnt = __popcll(masks[cent][lane]);
    int inc = cnt;
#pragma unroll
    for (int off = 1; off < 64; off <<= 1) {
      int n = __shfl_up(inc, off);
      if (lane >= off) inc += n;
    }
    offs[cent][lane] = inc - cnt;
  }
  __syncthreads();

  // --- first-K slots in global index order (each wave: its 16 chunks, both cents)
  for (int c = 0; c < 16; ++c) {
    int ch = w * 16 + c;
#pragma unroll
    for (int cent = 0; cent < 2; ++cent) {
      int base = offs[cent][ch];
      if (base >= NK) continue;
      u64 m = masks[cent][ch];
      if ((m >> lane) & 1ull) {
        int slot = base + __popcll(m & ((1ull << lane) - 1ull));
        if (slot < NK) idx_ls[cent][slot] = ch * 64 + lane;
      }
    }
  }
  __syncthreads();

  // --- gather concat [xyz_norm(3) | points(64)] into x0 (64 rows x 67)
  {
    int cent = t >> 7, tt = t & 127;
    int row = tt >> 2, q = tt & 3;               // 32 rows x 4 col-quarters
    int id = idx_ls[cent][row];
    int prow = (id < 0) ? (NP - 1) : id;         // torch -1 wrap
    const float4* p4 = (const float4*)(pts + ((size_t)b * NP + prow) * 64 + q * 16);
    float4 va = p4[0], vb = p4[1], vc = p4[2], vd = p4[3];
    float* dst = &x0[(cent * 32 + row) * 67 + 3 + q * 16];
    dst[0]  = va.x; dst[1]  = va.y; dst[2]  = va.z; dst[3]  = va.w;
    dst[4]  = vb.x; dst[5]  = vb.y; dst[6]  = vb.z; dst[7]  = vb.w;
    dst[8]  = vc.x; dst[9]  = vc.y; dst[10] = vc.z; dst[11] = vc.w;
    dst[12] = vd.x; dst[13] = vd.y; dst[14] = vd.z; dst[15] = vd.w;
    if (t < 64) {
      int c2 = t >> 5, slot = t & 31;
      int id2 = idx_ls[c2][slot];
      float ax = c2 ? c1x : c0x, ay = c2 ? c1y : c0y, az = c2 ? c1z : c0z;
      float gx, gy, gz;
      if (id2 >= 0) {
        gx = __fsub_rn(bx[id2 * 3 + 0], ax);
        gy = __fsub_rn(bx[id2 * 3 + 1], ay);
        gz = __fsub_rn(bx[id2 * 3 + 2], az);
      } else {
        gx = 0.0f - ax; gy = 0.0f - ay; gz = 0.0f - az;
      }
      float* d2p = &x0[(c2 * 32 + slot) * 67];
      d2p[0] = gx; d2p[1] = gy; d2p[2] = gz;
    }
  }
  __syncthreads();

  const int j0 = __builtin_amdgcn_readfirstlane(w * 16);   // wave-uniform col base
  const int R = lane;                                       // row 0..63

  // --- layer 1: 67 -> 64 (weights via scalar loads, uniform address)
  {
    float acc[16];
#pragma unroll
    for (int i = 0; i < 16; ++i) acc[i] = 0.0f;
    const float* xr = &x0[R * 67];
#pragma unroll 2
    for (int c = 0; c < 67; ++c) {
      float xv = xr[c];
      const float4* wr = (const float4*)(W0 + c * 64 + j0);
      float4 wa = wr[0], wb = wr[1], wc = wr[2], wd = wr[3];
      acc[0]  = fmaf(xv, wa.x, acc[0]);  acc[1]  = fmaf(xv, wa.y, acc[1]);
      acc[2]  = fmaf(xv, wa.z, acc[2]);  acc[3]  = fmaf(xv, wa.w, acc[3]);
      acc[4]  = fmaf(xv, wb.x, acc[4]);  acc[5]  = fmaf(xv, wb.y, acc[5]);
      acc[6]  = fmaf(xv, wb.z, acc[6]);  acc[7]  = fmaf(xv, wb.w, acc[7]);
      acc[8]  = fmaf(xv, wc.x, acc[8]);  acc[9]  = fmaf(xv, wc.y, acc[9]);
      acc[10] = fmaf(xv, wc.z, acc[10]); acc[11] = fmaf(xv, wc.w, acc[11]);
      acc[12] = fmaf(xv, wd.x, acc[12]); acc[13] = fmaf(xv, wd.y, acc[13]);
      acc[14] = fmaf(xv, wd.z, acc[14]); acc[15] = fmaf(xv, wd.w, acc[15]);
    }
#pragma unroll
    for (int i = 0; i < 16; ++i) {
      float y = fmaf(acc[i], sAB[j0 + i], sAB[64 + j0 + i]);
      x1[R * 65 + j0 + i] = fmaxf(y, 0.0f);
    }
  }
  __syncthreads();

  // --- layer 2: 64 -> 64, out into x0 region (stride 65)
  {
    float acc[16];
#pragma unroll
    for (int i = 0; i < 16; ++i) acc[i] = 0.0f;
    const float* xr = &x1[R * 65];
#pragma unroll 2
    for (int c = 0; c < 64; ++c) {
      float xv = xr[c];
      const float4* wr = (const float4*)(W1 + c * 64 + j0);
      float4 wa = wr[0], wb = wr[1], wc = wr[2], wd = wr[3];
      acc[0]  = fmaf(xv, wa.x, acc[0]);  acc[1]  = fmaf(xv, wa.y, acc[1]);
      acc[2]  = fmaf(xv, wa.z, acc[2]);  acc[3]  = fmaf(xv, wa.w, acc[3]);
      acc[4]  = fmaf(xv, wb.x, acc[4]);  acc[5]  = fmaf(xv, wb.y, acc[5]);
      acc[6]  = fmaf(xv, wb.z, acc[6]);  acc[7]  = fmaf(xv, wb.w, acc[7]);
      acc[8]  = fmaf(xv, wc.x, acc[8]);  acc[9]  = fmaf(xv, wc.y, acc[9]);
      acc[10] = fmaf(xv, wc.z, acc[10]); acc[11] = fmaf(xv, wc.w, acc[11]);
      acc[12] = fmaf(xv, wd.x, acc[12]); acc[13] = fmaf(xv, wd.y, acc[13]);
      acc[14] = fmaf(xv, wd.z, acc[14]); acc[15] = fmaf(xv, wd.w, acc[15]);
    }
#pragma unroll
    for (int i = 0; i < 16; ++i) {
      float y = fmaf(acc[i], sAB[128 + j0 + i], sAB[192 + j0 + i]);
      x0[R * 65 + j0 + i] = fmaxf(y, 0.0f);
    }
  }
  __syncthreads();

  // --- layer 3: 64 -> 128 + max over 32 rows per centroid (DPP halves)
  {
    const int j3 = __builtin_amdgcn_readfirstlane(w * 32);
    float acc[32];
#pragma unroll
    for (int i = 0; i < 32; ++i) acc[i] = 0.0f;
    const float* xr = &x0[R * 65];
    for (int c = 0; c < 64; ++c) {
      float xv = xr[c];
      const float4* wr = (const float4*)(W2 + c * 128 + j3);
#pragma unroll
      for (int q = 0; q < 8; ++q) {
        float4 wq = wr[q];
        acc[q * 4 + 0] = fmaf(xv, wq.x, acc[q * 4 + 0]);
        acc[q * 4 + 1] = fmaf(xv, wq.y, acc[q * 4 + 1]);
        acc[q * 4 + 2] = fmaf(xv, wq.z, acc[q * 4 + 2]);
        acc[q * 4 + 3] = fmaf(xv, wq.w, acc[q * 4 + 3]);
      }
    }
#pragma unroll
    for (int i = 0; i < 32; ++i) {
      float y = fmaf(acc[i], sAB[256 + j3 + i], sAB[384 + j3 + i]);
      u32 mb = __float_as_uint(fmaxf(y, 0.0f));   // >=0 -> bits order-isomorphic
      HALF_RED_UMAX32(mb);
      acc[i] = __uint_as_float(mb);
    }
    if (lane == 31 || lane == 63) {
      int cent = lane >> 5;
      float4* op = (float4*)(out1 + ((size_t)b * NS + s0 + cent) * 128 + j3);
#pragma unroll
      for (int q = 0; q < 8; ++q)
        op[q] = make_float4(acc[q * 4 + 0], acc[q * 4 + 1], acc[q * 4 + 2], acc[q * 4 + 3]);
    }
  }
}

// ---------------------------------------------------------------- launcher
extern "C" void kernel_launch(void* const* d_in, const int* in_sizes, int n_in,
                              void* d_out, int out_size, void* d_ws, size_t ws_size,
                              hipStream_t stream) {
  const float* xyz = (const float*)d_in[0];
  const float* pts = (const float*)d_in[1];
  const float* W0 = (const float*)d_in[2];  const float* b0 = (const float*)d_in[3];
  const float* g0 = (const float*)d_in[4];  const float* be0 = (const float*)d_in[5];
  const float* m0 = (const float*)d_in[6];  const float* v0 = (const float*)d_in[7];
  const float* W1 = (const float*)d_in[8];  const float* b1 = (const float*)d_in[9];
  const float* g1 = (const float*)d_in[10]; const float* be1 = (const float*)d_in[11];
  const float* m1 = (const float*)d_in[12]; const float* v1 = (const float*)d_in[13];
  const float* W2 = (const float*)d_in[14]; const float* b2 = (const float*)d_in[15];
  const float* g2 = (const float*)d_in[16]; const float* be2 = (const float*)d_in[17];
  const float* m2 = (const float*)d_in[18]; const float* v2 = (const float*)d_in[19];

  float* out0 = (float*)d_out;           // new_xyz    (B,S,3)
  float* out1 = out0 + NB * NS * 3;      // new_points (B,S,128)

  fps_kernel<<<NB, 512, 0, stream>>>(xyz, out0);

  group_mlp_kernel<<<NB * NS / 2, 256, 0, stream>>>(
      xyz, pts, out0,
      W0, b0, g0, be0, m0, v0,
      W1, b1, g1, be1, m1, v1,
      W2, b2, g2, be2, m2, v2,
      out1);
}